// Round 7
// baseline (281.987 us; speedup 1.0000x reference)
//
#include <hip/hip_runtime.h>
#include <cstdint>
#include <cstddef>

#define BM 64
#define BN 256
#define BK 32
#define NT 24                         // K-steps
#define THREADS 512
#define A_BYTES (BM * BK * 2)         // 4096
#define B_BYTES (BN * BK * 2)         // 16384
#define BUF_BYTES (A_BYTES + B_BYTES) // 20480
#define NBUF 3                        // 60 KB static LDS -> 2 blocks/CU

typedef __attribute__((ext_vector_type(4))) float f32x4;
typedef __attribute__((ext_vector_type(8))) short bf16x8;
typedef __attribute__((ext_vector_type(2))) unsigned int u32x2;

__device__ __forceinline__ unsigned int f2bf(float f) {
  union { float f; uint32_t u; } v; v.f = f;
  uint32_t r = v.u + 0x7FFFu + ((v.u >> 16) & 1u);   // RNE
  return r >> 16;
}

// WtS: per K-step kt (24 x 32k), 1024 16B-chunks, chunk c =
// [colgroup=c>>6][k8=(c>>4)&3][col=c&15] holding bf16
// W[kt*32+k8*8 .. +7][colgroup*16+col]. Identity order for glds + ds_read.
__global__ void wt_kernel(const float* __restrict__ W, unsigned short* __restrict__ WtS) {
  const int gid = blockIdx.x * 256 + threadIdx.x;   // 0..24575
  const int kt = gid >> 10;
  const int c  = gid & 1023;
  const int n  = ((c >> 6) << 4) | (c & 15);
  const int k0 = kt * 32 + ((c >> 4) & 3) * 8;
  unsigned int p[4];
#pragma unroll
  for (int i = 0; i < 4; ++i)
    p[i] = f2bf(W[(size_t)(k0 + 2 * i) * 256 + n]) |
           (f2bf(W[(size_t)(k0 + 2 * i + 1) * 256 + n]) << 16);
  *(u32x2*)((char*)WtS + (size_t)gid * 16)     = u32x2{p[0], p[1]};
  *(u32x2*)((char*)WtS + (size_t)gid * 16 + 8) = u32x2{p[2], p[3]};
}

// 8 waves (2 row-groups x 4 col-groups), wave tile 32x64 -> acc = 32 AGPR.
// 3-buffer LDS pipeline, prefetch distance 2, counted vmcnt(3), raw barrier.
__global__ __launch_bounds__(THREADS, 4) void edge_gemm(
    const float* __restrict__ srcf, const float* __restrict__ destf,
    const float* __restrict__ eaf, const float* __restrict__ uf,
    const int* __restrict__ batch, const unsigned short* __restrict__ WtS,
    const float* __restrict__ bias, float* __restrict__ out)
{
  __shared__ char smem[NBUF * BUF_BYTES];
  const int tid  = threadIdx.x;
  const int lane = tid & 63;
  const int w    = tid >> 6;
  const int wr   = w >> 2;      // 0..1 row-group (32 rows)
  const int wc   = w & 3;       // 0..3 col-group (64 cols)
  const int m0   = blockIdx.x * BM;
  const int l15  = lane & 15;
  const int l4   = lane >> 4;

  // A staging: thread tid owns 8B half-chunk -> LDS addr = tid*8 (linear).
  // chunk ci = tid>>1 = [rg:2][k8:2][r15:4]; half = tid&1.
  // rg = ci>>6 = tid>>7 (2 bits!), k8 = (tid>>5)&3, r15 = (tid>>1)&15.
  const int s_row  = ((tid >> 7) << 4) | ((tid >> 1) & 15);     // rg*16 + r15
  const int s_coff = (((tid >> 5) & 3) << 3) | ((tid & 1) << 2); // k8*8+half*4
  const int s_ae   = m0 + s_row;
  const int s_ub   = batch[s_ae];

  float bs[4];
#pragma unroll
  for (int nf = 0; nf < 4; ++nf) bs[nf] = bias[wc * 64 + nf * 16 + l15];

  f32x4 acc[2][4];
  f32x4 z = {0.f, 0.f, 0.f, 0.f};
#pragma unroll
  for (int i = 0; i < 2; ++i)
#pragma unroll
    for (int j = 0; j < 4; ++j) acc[i][j] = z;

  // concat = [dest(0..7), src(8..15), edge_attr(16..19), u[batch](20..23)]
  auto a_ptr = [&](int kt) -> const float* {
    if (kt < 8)  return destf + (size_t)s_ae * 256 + kt * 32 + s_coff;
    if (kt < 16) return srcf  + (size_t)s_ae * 256 + (kt - 8) * 32 + s_coff;
    if (kt < 20) return eaf   + (size_t)s_ae * 128 + (kt - 16) * 32 + s_coff;
    return uf + (size_t)s_ub * 128 + (kt - 20) * 32 + s_coff;
  };

  f32x4 va[2];   // full unroll -> static indexing (rule 20)

  // issue exactly 3 vmem ops: 2 glds (B) + 1 reg load (A)
  auto stage = [&](int kt) {
    char* Bb = smem + (kt % NBUF) * BUF_BYTES + A_BYTES;
    const char* wb = (const char*)WtS + (size_t)kt * B_BYTES;
#pragma unroll
    for (int j = 0; j < 2; ++j) {
      const char* g = wb + (size_t)(j * 512 + tid) * 16;
      char* l = Bb + (size_t)(j * 512 + w * 64) * 16;   // wave-uniform base
      __builtin_amdgcn_global_load_lds(
          (const __attribute__((address_space(1))) uint32_t*)g,
          (__attribute__((address_space(3))) uint32_t*)l, 16, 0, 0);
    }
    va[kt & 1] = *(const f32x4*)a_ptr(kt);
  };
  auto write_a = [&](int kt) {   // cvt + linear ds_write_b64 at tid*8
    char* Ab = smem + (kt % NBUF) * BUF_BYTES;
    f32x4 v = va[kt & 1];
    u32x2 p;
    p[0] = f2bf(v[0]) | (f2bf(v[1]) << 16);
    p[1] = f2bf(v[2]) | (f2bf(v[3]) << 16);
    *(u32x2*)(Ab + tid * 8) = p;   // compiler emits counted vmcnt for va here
  };
  auto compute = [&](int kt) {
    const char* Ab = smem + (kt % NBUF) * BUF_BYTES;
    const char* Bb = Ab + A_BYTES;
    bf16x8 af[2], bfr[4];
#pragma unroll
    for (int mf = 0; mf < 2; ++mf)   // contiguous 1KiB per wave: conflict-free
      af[mf] = *(const bf16x8*)(Ab + (((wr * 2 + mf) * 64) + l4 * 16 + l15) * 16);
#pragma unroll
    for (int nf = 0; nf < 4; ++nf)
      bfr[nf] = *(const bf16x8*)(Bb + (((wc * 4 + nf) * 64) + l4 * 16 + l15) * 16);
#pragma unroll
    for (int mf = 0; mf < 2; ++mf)
#pragma unroll
      for (int nf = 0; nf < 4; ++nf)
        acc[mf][nf] = __builtin_amdgcn_mfma_f32_16x16x32_bf16(
            af[mf], bfr[nf], acc[mf][nf], 0, 0, 0);
  };

#define STEP_SYNC()                                          \
  asm volatile("s_waitcnt vmcnt(3)" ::: "memory");           \
  __builtin_amdgcn_sched_barrier(0);                         \
  asm volatile("s_waitcnt lgkmcnt(0)" ::: "memory");         \
  __builtin_amdgcn_sched_barrier(0);                         \
  __builtin_amdgcn_s_barrier()

  // ---- prologue ----
  stage(0);
  __builtin_amdgcn_sched_barrier(0);
  stage(1);
  __builtin_amdgcn_sched_barrier(0);
  write_a(0);
  STEP_SYNC();

  // ---- main loop: never drains vmcnt to 0 ----
#pragma unroll
  for (int kt = 0; kt < NT; ++kt) {
    if (kt + 2 < NT) stage(kt + 2);
    __builtin_amdgcn_sched_barrier(0);
    compute(kt);
    if (kt + 1 < NT) {
      write_a(kt + 1);
      STEP_SYNC();
    }
  }

  // ---- epilogue: bias + ReLU; C/D layout col=lane&15, row=(lane>>4)*4+j ----
#pragma unroll
  for (int mf = 0; mf < 2; ++mf) {
    const int r0 = m0 + wr * 32 + mf * 16 + l4 * 4;
#pragma unroll
    for (int nf = 0; nf < 4; ++nf) {
      const int cn = wc * 64 + nf * 16 + l15;
      const f32x4 v = acc[mf][nf];
#pragma unroll
      for (int j = 0; j < 4; ++j) {
        const float x = v[j] + bs[nf];
        out[(size_t)(r0 + j) * 256 + cn] = x > 0.f ? x : 0.f;
      }
    }
  }
#undef STEP_SYNC
}

extern "C" void kernel_launch(void* const* d_in, const int* in_sizes, int n_in,
                              void* d_out, int out_size, void* d_ws, size_t ws_size,
                              hipStream_t stream) {
  const float* srcf  = (const float*)d_in[0];
  const float* destf = (const float*)d_in[1];
  const float* eaf   = (const float*)d_in[2];
  const float* uf    = (const float*)d_in[3];
  const int*   batch = (const int*)d_in[4];
  const float* W     = (const float*)d_in[5];
  const float* bias  = (const float*)d_in[6];
  float* out = (float*)d_out;
  unsigned short* WtS = (unsigned short*)d_ws;   // 24*16KB = 384 KB

  wt_kernel<<<96, 256, 0, stream>>>(W, WtS);

  edge_gemm<<<320000 / BM, THREADS, 0, stream>>>(
      srcf, destf, eaf, uf, batch, WtS, bias, out);
}